// Round 6
// baseline (1173.133 us; speedup 1.0000x reference)
//
#include <hip/hip_runtime.h>
#include <hip/hip_bf16.h>

typedef __hip_bfloat16 bf16;
typedef unsigned short u16;

#define N_NODES 100000
#define N_EDGES 1600000
#define F_IN 64
#define N_REL 8
#define N_GRAPH 256
#define N_HEAD 4
#define HC 128          // H*C
#define NBLK_SCAN 391   // ceil(100000/256)

__device__ __forceinline__ float lrelu(float x, float s) { return x >= 0.f ? x : s * x; }
__device__ __forceinline__ unsigned fenc(float f) {
  unsigned b = __float_as_uint(f);
  return (b & 0x80000000u) ? ~b : (b | 0x80000000u);
}
__device__ __forceinline__ float fdec(unsigned u) {
  float v = __uint_as_float((u & 0x80000000u) ? (u & 0x7fffffffu) : ~u);
  return fmaxf(fminf(v, 3e38f), -3e38f);
}
__device__ __forceinline__ float bf2f(bf16 v) { return __bfloat162float(v); }
__device__ __forceinline__ bf16 f2bf(float v) { return __float2bfloat16(v); }
__device__ __forceinline__ float lo_bf(unsigned u) { return __uint_as_float(u << 16); }
__device__ __forceinline__ float hi_bf(unsigned u) { return __uint_as_float(u & 0xFFFF0000u); }
__device__ __forceinline__ unsigned f2bfu(float v) {
  unsigned u = __float_as_uint(v);
  return (u + 0x7FFFu + ((u >> 16) & 1u)) >> 16;
}

// dtype-adaptive loads: BF=true -> bf16 array; BF=false -> fp32 array
template<bool BF> __device__ __forceinline__ float ldf(const void* p, size_t i) {
  if (BF) { u16 v = ((const u16*)p)[i]; return __uint_as_float(((unsigned)v) << 16); }
  else    { return ((const float*)p)[i]; }
}
// PAIR-index semantics: returns elements {2i, 2i+1}
template<bool BF> __device__ __forceinline__ float2 ldf2(const void* p, size_t i) {
  if (BF) { unsigned v = ((const unsigned*)p)[i]; return make_float2(lo_bf(v), hi_bf(v)); }
  else    { return ((const float2*)p)[i]; }
}

// ---- dtype probe ----
__global__ void k_probe(const u16* __restrict__ xr, int* __restrict__ flag) {
  int t = threadIdx.x;
  int c = 0;
  for (int i = t; i < 1024; i += 256) {
    unsigned e = (xr[i] >> 7) & 0xFFu;
    if (e >= 100u && e <= 140u) c++;
  }
  __shared__ int sc[256];
  sc[t] = c;
  __syncthreads();
  for (int s = 128; s; s >>= 1) { if (t < s) sc[t] += sc[t + s]; __syncthreads(); }
  if (t == 0) *flag = (sc[0] >= 800) ? 1 : 0;
}

// ---- GAT node transform: 16 nodes / 256 threads, weight columns in registers ----
template<bool BF>
__device__ __forceinline__ void gat_body(const void* x, const void* w, const void* att_s,
                                         const void* att_d, u16* __restrict__ h,
                                         float* __restrict__ a_src, float* __restrict__ a_dst,
                                         int n0, float* xs) {
  int tid = threadIdx.x;
  for (int i = tid; i < 16 * F_IN; i += 256)
    xs[i] = ldf<BF>(x, (size_t)(n0 + (i >> 6)) * F_IN + (i & 63));
  __syncthreads();
  int g = tid >> 7, c = tid & 127;
  float as_c = ldf<BF>(att_s, c), ad_c = ldf<BF>(att_d, c);
  float acc[8] = {0.f, 0.f, 0.f, 0.f, 0.f, 0.f, 0.f, 0.f};
#pragma unroll 1
  for (int kh = 0; kh < F_IN; kh += 32) {
    float wreg[32];
#pragma unroll
    for (int j = 0; j < 32; ++j) wreg[j] = ldf<BF>(w, (size_t)(kh + j) * HC + c);
#pragma unroll
    for (int n = 0; n < 8; ++n) {
      const float* xr = &xs[(g * 8 + n) * F_IN + kh];
#pragma unroll
      for (int j = 0; j < 32; j += 4) {
        float4 xv = *(const float4*)&xr[j];
        acc[n] += xv.x * wreg[j];
        acc[n] += xv.y * wreg[j + 1];
        acc[n] += xv.z * wreg[j + 2];
        acc[n] += xv.w * wreg[j + 3];
      }
    }
  }
  int l = tid & 63, head = c >> 5;
#pragma unroll
  for (int n = 0; n < 8; ++n) {
    int node = n0 + g * 8 + n;
    h[(size_t)node * HC + c] = (u16)f2bfu(acc[n]);
    float ps = acc[n] * as_c, pd = acc[n] * ad_c;
#pragma unroll
    for (int off = 16; off > 0; off >>= 1) {
      ps += __shfl_xor(ps, off, 64);
      pd += __shfl_xor(pd, off, 64);
    }
    if ((l & 31) == 0) {
      a_src[node * N_HEAD + head] = ps;
      a_dst[node * N_HEAD + head] = pd;
    }
  }
}

// ---- merged: hist (blocks 0..6249) + gat (6250..12499) ----
__global__ void __launch_bounds__(256, 4)
k_gh(const void* x, const void* w, const void* att_s, const void* att_d,
     u16* h, float* a_src, float* a_dst,
     const int* __restrict__ ei, const int* __restrict__ etype,
     int* __restrict__ deg, int* __restrict__ cnt, const int* flag) {
  __shared__ __align__(16) float xs[16 * F_IN];
  int bid = blockIdx.x;
  if (bid < 6250) {
    int e = bid * 256 + threadIdx.x;   // 6250*256 == N_EDGES exactly
    int d = ei[N_EDGES + e], t = etype[e];
    atomicAdd(&deg[d], 1);
    atomicAdd(&cnt[d * N_REL + t], 1);
  } else {
    int n0 = (bid - 6250) * 16;
    if (__builtin_amdgcn_readfirstlane(*flag))
      gat_body<true>(x, w, att_s, att_d, h, a_src, a_dst, n0, xs);
    else
      gat_body<false>(x, w, att_s, att_d, h, a_src, a_dst, n0, xs);
  }
}

// ---- RGCN1 transform: 16 nodes x ALL 8 relations / 256 threads ----
template<bool BF>
__device__ __forceinline__ void xw1_body(const void* x, const void* rw1, bf16* __restrict__ xw1,
                                         int n0, float* xs) {
  int tid = threadIdx.x;
  for (int i = tid; i < 16 * F_IN; i += 256)
    xs[i] = ldf<BF>(x, (size_t)(n0 + (i >> 6)) * F_IN + (i & 63));
  __syncthreads();
  int r = tid >> 5, c = tid & 31;
  float acc[16] = {0.f, 0.f, 0.f, 0.f, 0.f, 0.f, 0.f, 0.f,
                   0.f, 0.f, 0.f, 0.f, 0.f, 0.f, 0.f, 0.f};
#pragma unroll 1
  for (int kh = 0; kh < F_IN; kh += 32) {
    float wreg[32];
#pragma unroll
    for (int j = 0; j < 32; ++j)
      wreg[j] = ldf<BF>(rw1, (size_t)(r * F_IN + kh + j) * 32 + c);
#pragma unroll
    for (int n = 0; n < 16; ++n) {
      const float* xr = &xs[n * F_IN + kh];
#pragma unroll
      for (int j = 0; j < 32; j += 4) {
        float4 xv = *(const float4*)&xr[j];
        acc[n] += xv.x * wreg[j];
        acc[n] += xv.y * wreg[j + 1];
        acc[n] += xv.z * wreg[j + 2];
        acc[n] += xv.w * wreg[j + 3];
      }
    }
  }
#pragma unroll
  for (int n = 0; n < 16; ++n)
    xw1[((size_t)r * N_NODES + (n0 + n)) * 32 + c] = f2bf(acc[n]);
}

// ---- 2-level exclusive scan ----
__global__ void k_scan_a(const int* __restrict__ deg, int* __restrict__ rowptr,
                         int* __restrict__ scanblk) {
  __shared__ int buf[256];
  int tid = threadIdx.x;
  int i = blockIdx.x * 256 + tid;
  int v = (i < N_NODES) ? deg[i] : 0;
  buf[tid] = v;
  __syncthreads();
  for (int st = 1; st < 256; st <<= 1) {
    int t = buf[tid];
    int a = (tid >= st) ? buf[tid - st] : 0;
    __syncthreads();
    buf[tid] = t + a;
    __syncthreads();
  }
  if (i < N_NODES) rowptr[i] = buf[tid] - v;
  if (tid == 255) scanblk[blockIdx.x] = buf[255];
}
__global__ void k_scan_b(int* __restrict__ scanblk) {
  __shared__ int buf[512];
  int tid = threadIdx.x;
  int v = (tid < NBLK_SCAN) ? scanblk[tid] : 0;
  buf[tid] = v;
  __syncthreads();
  for (int st = 1; st < 512; st <<= 1) {
    int t = buf[tid];
    int a = (tid >= st) ? buf[tid - st] : 0;
    __syncthreads();
    buf[tid] = t + a;
    __syncthreads();
  }
  if (tid < NBLK_SCAN) scanblk[tid] = buf[tid] - v;
}
__global__ void k_scan_c(int* __restrict__ rowptr, int* __restrict__ wp,
                         const int* __restrict__ scanblk) {
  int i = blockIdx.x * 256 + threadIdx.x;
  if (i < N_NODES) {
    int val = rowptr[i] + scanblk[blockIdx.x];
    rowptr[i] = val;
    wp[i] = val;
  } else if (i == N_NODES) {
    rowptr[N_NODES] = N_EDGES;
  }
}

// ---- merged: scatter (blocks 0..6249, latency-bound) + xw1 (6250..12499, VALU) ----
__global__ void __launch_bounds__(256, 4)
k_scatxw1(const int* __restrict__ ei, const int* __restrict__ etype,
          const float* __restrict__ a_src, const float* __restrict__ a_dst,
          int* __restrict__ wp, unsigned* __restrict__ csr, float4* __restrict__ p_logit,
          const void* x, const void* rw1, bf16* xw1, const int* flag) {
  __shared__ __align__(16) float xs[16 * F_IN];
  int bid = blockIdx.x;
  if (bid < 6250) {
    int e = bid * 256 + threadIdx.x;   // exact
    int sn = ei[e], d = ei[N_EDGES + e], t = etype[e];
    int pos = atomicAdd(&wp[d], 1);
    csr[pos] = (unsigned)sn | ((unsigned)t << 20);
    const float4 as = *(const float4*)&a_src[sn * 4];
    const float4 ad = *(const float4*)&a_dst[d * 4];
    float4 lg;
    lg.x = lrelu(as.x + ad.x, 0.2f);
    lg.y = lrelu(as.y + ad.y, 0.2f);
    lg.z = lrelu(as.z + ad.z, 0.2f);
    lg.w = lrelu(as.w + ad.w, 0.2f);
    p_logit[pos] = lg;
  } else {
    int n0 = (bid - 6250) * 16;
    if (__builtin_amdgcn_readfirstlane(*flag)) xw1_body<true>(x, rw1, xw1, n0, xs);
    else xw1_body<false>(x, rw1, xw1, n0, xs);
  }
}

// ---- GAT aggregate with inline segment softmax (round-2 proven shape) ----
template<bool BF>
__device__ __forceinline__ void agg_body(const int* __restrict__ rowptr,
                                         const unsigned* __restrict__ csr,
                                         const float* __restrict__ plog,
                                         const uint2* __restrict__ hu2, const void* gbias,
                                         const void* d1w, const void* d1b,
                                         const int* __restrict__ batch,
                                         unsigned* __restrict__ gmax, int* __restrict__ npg,
                                         float (*os)[132], int bid) {
  int tid = threadIdx.x;
  int wave = tid >> 6, l = tid & 63;
  int d = bid * 4 + wave;
  int base = rowptr[d];
  int deg = rowptr[d + 1] - base;
  // --- softmax stats in-register ---
  float m = -1e30f, si;
  {
    int hd = l & 3, sl = l >> 2;
    for (int i = sl; i < deg; i += 16) m = fmaxf(m, plog[(size_t)(base + i) * 4 + hd]);
    m = fmaxf(m, __shfl_xor(m, 4, 64));
    m = fmaxf(m, __shfl_xor(m, 8, 64));
    m = fmaxf(m, __shfl_xor(m, 16, 64));
    m = fmaxf(m, __shfl_xor(m, 32, 64));
    float s = 0.f;
    for (int i = sl; i < deg; i += 16) s += __expf(plog[(size_t)(base + i) * 4 + hd] - m);
    s += __shfl_xor(s, 4, 64);
    s += __shfl_xor(s, 8, 64);
    s += __shfl_xor(s, 16, 64);
    s += __shfl_xor(s, 32, 64);
    si = (deg > 0) ? 1.f / s : 0.f;
  }
  int slot = l >> 5, cl = l & 31;   // lane covers channels 4cl..4cl+3 of edge-slot `slot`
  int head = cl >> 3;
  float mh = __shfl(m, head, 64);   // lane 0..3 holds fully-reduced (m,si) for head 0..3
  float sih = __shfl(si, head, 64);
  float a0 = 0.f, a1 = 0.f, a2 = 0.f, a3 = 0.f;
  int i = slot;
  for (; i + 6 < deg; i += 8) {
    unsigned sp0 = csr[base + i],     sp1 = csr[base + i + 2];
    unsigned sp2 = csr[base + i + 4], sp3 = csr[base + i + 6];
    float av0 = __expf(plog[(size_t)(base + i) * 4 + head] - mh) * sih;
    float av1 = __expf(plog[(size_t)(base + i + 2) * 4 + head] - mh) * sih;
    float av2 = __expf(plog[(size_t)(base + i + 4) * 4 + head] - mh) * sih;
    float av3 = __expf(plog[(size_t)(base + i + 6) * 4 + head] - mh) * sih;
    uint2 h0 = hu2[(size_t)(sp0 & 0xFFFFF) * 32 + cl];
    uint2 h1 = hu2[(size_t)(sp1 & 0xFFFFF) * 32 + cl];
    uint2 h2 = hu2[(size_t)(sp2 & 0xFFFFF) * 32 + cl];
    uint2 h3 = hu2[(size_t)(sp3 & 0xFFFFF) * 32 + cl];
    a0 += lo_bf(h0.x) * av0 + lo_bf(h1.x) * av1 + lo_bf(h2.x) * av2 + lo_bf(h3.x) * av3;
    a1 += hi_bf(h0.x) * av0 + hi_bf(h1.x) * av1 + hi_bf(h2.x) * av2 + hi_bf(h3.x) * av3;
    a2 += lo_bf(h0.y) * av0 + lo_bf(h1.y) * av1 + lo_bf(h2.y) * av2 + lo_bf(h3.y) * av3;
    a3 += hi_bf(h0.y) * av0 + hi_bf(h1.y) * av1 + hi_bf(h2.y) * av2 + hi_bf(h3.y) * av3;
  }
  for (; i < deg; i += 2) {
    unsigned sp = csr[base + i];
    float av = __expf(plog[(size_t)(base + i) * 4 + head] - mh) * sih;
    uint2 hv = hu2[(size_t)(sp & 0xFFFFF) * 32 + cl];
    a0 += lo_bf(hv.x) * av;
    a1 += hi_bf(hv.x) * av;
    a2 += lo_bf(hv.y) * av;
    a3 += hi_bf(hv.y) * av;
  }
  a0 += __shfl_xor(a0, 32, 64);
  a1 += __shfl_xor(a1, 32, 64);
  a2 += __shfl_xor(a2, 32, 64);
  a3 += __shfl_xor(a3, 32, 64);
  if (slot == 0) {
    os[wave][4 * cl + 0] = lrelu(a0 + ldf<BF>(gbias, 4 * cl + 0), 0.01f);
    os[wave][4 * cl + 1] = lrelu(a1 + ldf<BF>(gbias, 4 * cl + 1), 0.01f);
    os[wave][4 * cl + 2] = lrelu(a2 + ldf<BF>(gbias, 4 * cl + 2), 0.01f);
    os[wave][4 * cl + 3] = lrelu(a3 + ldf<BF>(gbias, 4 * cl + 3), 0.01f);
  }
  __syncthreads();
  if (tid < 64) {
    int node = tid >> 4, out = tid & 15;
    float acc = ldf<BF>(d1b, out);
#pragma unroll
    for (int k = 0; k < HC; ++k) acc += os[node][k] * ldf<BF>(d1w, (size_t)k * 16 + out);
    acc = lrelu(acc, 0.01f);
    atomicMax(&gmax[batch[bid * 4 + node] * 16 + out], fenc(acc));
  }
  if (tid < 4) atomicAdd(&npg[batch[bid * 4 + tid]], 1);
}

// ---- RGCN1 gather (round-2 proven shape) + optional fused zw2 tail (uint stores) ----
template<bool BF>
__device__ __forceinline__ void ragg1_body(const int* __restrict__ rowptr,
                                           const unsigned* __restrict__ csr,
                                           const int* __restrict__ cnt,
                                           const unsigned* __restrict__ xw, const void* x,
                                           const void* root1, const void* rb1,
                                           const void* rw2, bf16* __restrict__ zw2t,
                                           float* __restrict__ z1, float* sh,
                                           float (*z1l)[32], int bid) {
  float (*xs)[F_IN] = (float(*)[F_IN])sh;
  float (*cinv)[N_REL] = (float(*)[N_REL])(sh + 4 * F_IN);
  int tid = threadIdx.x;
  int n0 = bid * 4;  // 25000 blocks, exact
  {
    int nn = n0 + (tid >> 6);
    xs[tid >> 6][tid & 63] = ldf<BF>(x, (size_t)nn * F_IN + (tid & 63));
  }
  if (tid < 32) {
    int cv = cnt[(n0 + (tid >> 3)) * N_REL + (tid & 7)];
    cinv[tid >> 3][tid & 7] = (cv > 0) ? 1.f / (float)cv : 0.f;
  }
  __syncthreads();
  int wave = tid >> 6, l = tid & 63;
  int slot = l >> 4, cl = l & 15;   // channels 2cl, 2cl+1
  int n = n0 + wave;
  int base = rowptr[n], deg = rowptr[n + 1] - base;
  float a0 = 0.f, a1 = 0.f;
  int i = slot;
  for (; i + 4 < deg; i += 8) {
    unsigned sp0 = csr[base + i], sp1 = csr[base + i + 4];
    int t0 = sp0 >> 20, t1 = sp1 >> 20;
    unsigned v0 = xw[((size_t)t0 * N_NODES + (sp0 & 0xFFFFF)) * 16 + cl];
    unsigned v1 = xw[((size_t)t1 * N_NODES + (sp1 & 0xFFFFF)) * 16 + cl];
    float c0 = cinv[wave][t0], c1 = cinv[wave][t1];
    a0 += lo_bf(v0) * c0 + lo_bf(v1) * c1;
    a1 += hi_bf(v0) * c0 + hi_bf(v1) * c1;
  }
  if (i < deg) {
    unsigned sp = csr[base + i];
    int t = sp >> 20;
    unsigned v = xw[((size_t)t * N_NODES + (sp & 0xFFFFF)) * 16 + cl];
    float c0 = cinv[wave][t];
    a0 += lo_bf(v) * c0;
    a1 += hi_bf(v) * c0;
  }
  // root part: slot covers k in [slot*16, slot*16+16)
#pragma unroll
  for (int kk = 0; kk < 16; ++kk) {
    int k = slot * 16 + kk;
    float xv = xs[wave][k];
    float2 wv = ldf2<BF>(root1, (size_t)k * 16 + cl);   // pair idx: elements k*32+2cl,+1
    a0 += xv * wv.x;
    a1 += xv * wv.y;
  }
  a0 += __shfl_xor(a0, 16, 64); a0 += __shfl_xor(a0, 32, 64);
  a1 += __shfl_xor(a1, 16, 64); a1 += __shfl_xor(a1, 32, 64);
  if (slot == 0) {
    float v0 = fmaxf(a0 + ldf<BF>(rb1, 2 * cl), 0.f);
    float v1 = fmaxf(a1 + ldf<BF>(rb1, 2 * cl + 1), 0.f);
    z1[(size_t)n * 32 + 2 * cl]     = v0;
    z1[(size_t)n * 32 + 2 * cl + 1] = v1;
    z1l[wave][2 * cl]     = v0;
    z1l[wave][2 * cl + 1] = v1;
  }
  // ---- fused zw2 tail (only when workspace headroom allows a separate zw2 region) ----
  if (zw2t) {
    __syncthreads();
    unsigned* zw2u = (unsigned*)zw2t;
    int o = tid;                      // 256 threads: r = o>>5, node = (o>>3)&3, cp = o&7
    int r = o >> 5, node = (o >> 3) & 3, cp = o & 7;
    float acc0 = 0.f, acc1 = 0.f;
#pragma unroll
    for (int k = 0; k < 32; ++k) {
      float zv = z1l[node][k];
      // rw2 element index of ch 2cp at row (r,k) = (r*32+k)*16 + 2cp -> PAIR index /2:
      float2 wv = ldf2<BF>(rw2, (size_t)(r * 32 + k) * 8 + cp);
      acc0 += zv * wv.x;
      acc1 += zv * wv.y;
    }
    zw2u[((size_t)r * N_NODES + (n0 + node)) * 8 + cp] = f2bfu(acc0) | (f2bfu(acc1) << 16);
  }
}

// ---- merged: GAT aggregate (blocks 0..24999) + RGCN1 gather [+zw2] (25000..49999) ----
__global__ void k_aggragg1(const int* rowptr, const unsigned* csr, const float* plog,
                           const u16* h, const void* gbias, const void* d1w, const void* d1b,
                           const int* batch, unsigned* gmax, int* npg,
                           const int* cnt, const bf16* xw1, const void* x,
                           const void* root1, const void* rb1, const void* rw2, bf16* zw2t,
                           float* z1, const int* flag) {
  __shared__ __align__(16) float sh[544];   // union: os[4][132]=528 | xs[4][64]+cinv[4][8]=288
  __shared__ __align__(16) float z1l[4][32];
  int bf = __builtin_amdgcn_readfirstlane(*flag);
  if (blockIdx.x < 25000) {
    if (bf) agg_body<true>(rowptr, csr, plog, (const uint2*)h, gbias, d1w, d1b,
                           batch, gmax, npg, (float(*)[132])sh, blockIdx.x);
    else    agg_body<false>(rowptr, csr, plog, (const uint2*)h, gbias, d1w, d1b,
                            batch, gmax, npg, (float(*)[132])sh, blockIdx.x);
  } else {
    if (bf) ragg1_body<true>(rowptr, csr, cnt, (const unsigned*)xw1, x, root1, rb1,
                             rw2, zw2t, z1, sh, z1l, blockIdx.x - 25000);
    else    ragg1_body<false>(rowptr, csr, cnt, (const unsigned*)xw1, x, root1, rb1,
                              rw2, zw2t, z1, sh, z1l, blockIdx.x - 25000);
  }
}

// ---- RGCN2 transform fallback (when no workspace headroom): zw2 = z1 @ rw2 ----
template<bool BF>
__device__ __forceinline__ void zw2_body(const float* __restrict__ z1, const void* rw2,
                                         bf16* __restrict__ zw2) {
  __shared__ float zs[16][32];
  int tid = threadIdx.x;
  int n0 = blockIdx.x * 16;
  for (int i = tid; i < 16 * 32; i += 256) {
    int nn = n0 + (i >> 5);
    zs[i >> 5][i & 31] = (nn < N_NODES) ? z1[(size_t)nn * 32 + (i & 31)] : 0.f;
  }
  __syncthreads();
  int nl = tid >> 4, c = tid & 15;
  int n = n0 + nl, r = blockIdx.y;
  float acc = 0.f;
#pragma unroll
  for (int k = 0; k < 32; ++k) acc += zs[nl][k] * ldf<BF>(rw2, (size_t)(r * 32 + k) * 16 + c);
  if (n < N_NODES) zw2[((size_t)r * N_NODES + n) * 16 + c] = f2bf(acc);
}
__global__ void k_zw2(const float* z1, const void* rw2, bf16* zw2, const int* flag) {
  if (__builtin_amdgcn_readfirstlane(*flag)) zw2_body<true>(z1, rw2, zw2);
  else zw2_body<false>(z1, rw2, zw2);
}

// ---- RGCN2 gather (round-2 proven shape): 4 nodes/block, 8 slots x 8 lanes x u32 ----
template<bool BF>
__device__ __forceinline__ void ragg2_body(const int* __restrict__ rowptr,
                                           const unsigned* __restrict__ csr,
                                           const int* __restrict__ cnt,
                                           const unsigned* __restrict__ zw,
                                           const float* __restrict__ z1, const void* root2,
                                           const void* rb2, const int* __restrict__ batch,
                                           float* __restrict__ gsum) {
  __shared__ float zs[4][33];
  __shared__ float cinv[4][N_REL];
  int tid = threadIdx.x;
  int n0 = blockIdx.x * 4;  // grid 25000, exact
  if (tid < 128) {
    int nn = n0 + (tid >> 5);
    zs[tid >> 5][tid & 31] = z1[(size_t)nn * 32 + (tid & 31)];
  }
  if (tid < 32) {
    int cv = cnt[(n0 + (tid >> 3)) * N_REL + (tid & 7)];
    cinv[tid >> 3][tid & 7] = (cv > 0) ? 1.f / (float)cv : 0.f;
  }
  __syncthreads();
  int wave = tid >> 6, l = tid & 63;
  int slot = l >> 3, cl = l & 7;   // channels 2cl, 2cl+1 of 16
  int n = n0 + wave;
  int base = rowptr[n], deg = rowptr[n + 1] - base;
  float a0 = 0.f, a1 = 0.f;
  int i = slot;
  for (; i + 8 < deg; i += 16) {
    unsigned sp0 = csr[base + i], sp1 = csr[base + i + 8];
    int t0 = sp0 >> 20, t1 = sp1 >> 20;
    unsigned v0 = zw[((size_t)t0 * N_NODES + (sp0 & 0xFFFFF)) * 8 + cl];
    unsigned v1 = zw[((size_t)t1 * N_NODES + (sp1 & 0xFFFFF)) * 8 + cl];
    float c0 = cinv[wave][t0], c1 = cinv[wave][t1];
    a0 += lo_bf(v0) * c0 + lo_bf(v1) * c1;
    a1 += hi_bf(v0) * c0 + hi_bf(v1) * c1;
  }
  if (i < deg) {
    unsigned sp = csr[base + i];
    int t = sp >> 20;
    unsigned v = zw[((size_t)t * N_NODES + (sp & 0xFFFFF)) * 8 + cl];
    float c0 = cinv[wave][t];
    a0 += lo_bf(v) * c0;
    a1 += hi_bf(v) * c0;
  }
  // root part: slot covers k in [slot*4, slot*4+4)
#pragma unroll
  for (int kk = 0; kk < 4; ++kk) {
    int k = slot * 4 + kk;
    float zv = zs[wave][k];
    float2 wv = ldf2<BF>(root2, (size_t)k * 8 + cl);   // pair idx: elements k*16+2cl,+1
    a0 += zv * wv.x;
    a1 += zv * wv.y;
  }
  a0 += __shfl_xor(a0, 8, 64); a0 += __shfl_xor(a0, 16, 64); a0 += __shfl_xor(a0, 32, 64);
  a1 += __shfl_xor(a1, 8, 64); a1 += __shfl_xor(a1, 16, 64); a1 += __shfl_xor(a1, 32, 64);
  if (slot == 0) {
    float z2a = fmaxf(a0 + ldf<BF>(rb2, 2 * cl), 0.f);
    float z2b = fmaxf(a1 + ldf<BF>(rb2, 2 * cl + 1), 0.f);
    int g = batch[n];
    atomicAdd(&gsum[g * 16 + 2 * cl], z2a);
    atomicAdd(&gsum[g * 16 + 2 * cl + 1], z2b);
  }
}
__global__ void k_ragg2(const int* rowptr, const unsigned* csr, const int* cnt,
                        const bf16* zw2, const float* z1, const void* root2, const void* rb2,
                        const int* batch, float* gsum, const int* flag) {
  if (__builtin_amdgcn_readfirstlane(*flag))
    ragg2_body<true>(rowptr, csr, cnt, (const unsigned*)zw2, z1, root2, rb2, batch, gsum);
  else
    ragg2_body<false>(rowptr, csr, cnt, (const unsigned*)zw2, z1, root2, rb2, batch, gsum);
}

// ---- final ----
template<bool BF>
__device__ __forceinline__ void final_body(const unsigned* __restrict__ gmax,
                                           const float* __restrict__ gsum,
                                           const int* __restrict__ npg, const void* dw,
                                           const void* db, void* out) {
  int g = threadIdx.x;
  if (g >= N_GRAPH) return;
  float acc = ldf<BF>(db, 0);
  int np = npg[g]; if (np < 1) np = 1;
  float inv = 1.f / (float)np;
#pragma unroll
  for (int c = 0; c < 16; ++c) {
    acc += fdec(gmax[g * 16 + c]) * ldf<BF>(dw, c);
    acc += (gsum[g * 16 + c] * inv) * ldf<BF>(dw, 16 + c);
  }
  if (BF) ((bf16*)out)[g] = f2bf(acc);
  else ((float*)out)[g] = acc;
}
__global__ void k_final(const unsigned* gmax, const float* gsum, const int* npg,
                        const void* dw, const void* db, void* out, const int* flag) {
  if (__builtin_amdgcn_readfirstlane(*flag)) final_body<true>(gmax, gsum, npg, dw, db, out);
  else final_body<false>(gmax, gsum, npg, dw, db, out);
}

extern "C" void kernel_launch(void* const* d_in, const int* in_sizes, int n_in,
                              void* d_out, int out_size, void* d_ws, size_t ws_size,
                              hipStream_t stream) {
  const void* x        = d_in[0];
  const int*  ei       = (const int*)d_in[1];
  const int*  etype    = (const int*)d_in[2];
  const int*  batch    = (const int*)d_in[3];
  const void* gat_w    = d_in[4];
  const void* att_src  = d_in[5];
  const void* att_dst  = d_in[6];
  const void* gat_bias = d_in[7];
  const void* d1w      = d_in[8];
  const void* d1b      = d_in[9];
  const void* rw1      = d_in[10];
  const void* root1    = d_in[11];
  const void* rb1      = d_in[12];
  const void* rw2      = d_in[13];
  const void* root2    = d_in[14];
  const void* rb2      = d_in[15];
  const void* dw       = d_in[16];
  const void* db       = d_in[17];

  // ---- workspace layout (base ~129.2 MB; +25.6 MB zw2 region if headroom) ----
  char* ws = (char*)d_ws;
  const size_t o_h     = 0;           // u16  N*128 (25.6MB)  — GAT h table
  const size_t o_plog  = 25600000;    // f32  E*4   (25.6MB)  — logits per CSR pos
  const size_t o_xw1   = 51200000;    // bf16 R*N*32 (51.2MB) — RGCN1 per-relation transform
  const size_t o_asrc  = 102400000;   // f32 N*4 (1.6MB)
  const size_t o_adst  = 104000000;   // f32 N*4 (1.6MB)
  const size_t o_deg   = 105600000;   // i32 N (0.4MB)
  const size_t o_rowp  = 106000000;   // i32 N+1
  const size_t o_wp    = 106400016;   // i32 N
  const size_t o_cnt   = 106800016;   // i32 N*8 (3.2MB)
  const size_t o_csr   = 110000016;   // u32 E (6.4MB)
  const size_t o_z1    = 116400016;   // f32 N*32 (12.8MB)
  const size_t o_sblk  = 129200016;   // i32 NBLK_SCAN
  const size_t o_gmax  = 129201600;   // u32 G*16
  const size_t o_gsum  = 129217984;   // f32 G*16
  const size_t o_npg   = 129234368;   // i32 G
  const size_t o_flag  = 129235392;   // i32
  const size_t total1  = 129235396;
  const size_t o_zw2s  = 129235456;   // bf16 R*N*16 (25.6MB) — separate zw2 (fused path)
  const size_t total2  = o_zw2s + 25600000;
  if (ws_size < total1) return;
  const bool fused = (ws_size >= total2);

  u16*      h      = (u16*)(ws + o_h);
  float*    plog   = (float*)(ws + o_plog);
  bf16*     xw1    = (bf16*)(ws + o_xw1);
  float*    a_src  = (float*)(ws + o_asrc);
  float*    a_dst  = (float*)(ws + o_adst);
  int*      deg    = (int*)(ws + o_deg);
  int*      rowptr = (int*)(ws + o_rowp);
  int*      wp     = (int*)(ws + o_wp);
  int*      cnt    = (int*)(ws + o_cnt);
  unsigned* csr    = (unsigned*)(ws + o_csr);
  float*    z1     = (float*)(ws + o_z1);
  int*      sblk   = (int*)(ws + o_sblk);
  unsigned* gmax   = (unsigned*)(ws + o_gmax);
  float*    gsum   = (float*)(ws + o_gsum);
  int*      npg    = (int*)(ws + o_npg);
  int*      flag   = (int*)(ws + o_flag);
  bf16*     zw2    = fused ? (bf16*)(ws + o_zw2s) : (bf16*)(ws + o_h);  // fallback overlays h

  // dtype probe
  k_probe<<<1, 256, 0, stream>>>((const u16*)x, flag);

  // zero-init: deg..cnt contiguous, and gmax/gsum/npg
  hipMemsetAsync(ws + o_deg, 0, o_csr - o_deg, stream);
  hipMemsetAsync(ws + o_gmax, 0, 33792, stream);

  // merged: edge histogram + GAT node transform
  k_gh<<<12500, 256, 0, stream>>>(x, gat_w, att_src, att_dst, h, a_src, a_dst,
                                  ei, etype, deg, cnt, flag);

  // CSR scan
  k_scan_a<<<NBLK_SCAN, 256, 0, stream>>>(deg, rowptr, sblk);
  k_scan_b<<<1, 512, 0, stream>>>(sblk);
  k_scan_c<<<NBLK_SCAN, 256, 0, stream>>>(rowptr, wp, sblk);

  // merged: scatter (latency-bound) + RGCN1 transform (VALU-bound) — overlap
  k_scatxw1<<<12500, 256, 0, stream>>>(ei, etype, a_src, a_dst, wp, csr, (float4*)plog,
                                       x, rw1, xw1, flag);

  // merged: GAT aggregate + RGCN1 gather (+ fused zw2 tail when headroom)
  k_aggragg1<<<50000, 256, 0, stream>>>(rowptr, csr, plog, h, gat_bias, d1w, d1b,
                                        batch, gmax, npg, cnt, xw1, x, root1, rb1,
                                        rw2, fused ? zw2 : (bf16*)nullptr, z1, flag);

  // RGCN2 transform fallback path (zw2 overlays h — GAT phase done)
  if (!fused)
    k_zw2<<<dim3((N_NODES + 15) / 16, N_REL), 256, 0, stream>>>(z1, rw2, zw2, flag);

  // RGCN2 gather
  k_ragg2<<<N_NODES / 4, 256, 0, stream>>>(rowptr, csr, cnt, zw2, z1, root2, rb2,
                                           batch, gsum, flag);

  // fuse
  k_final<<<1, 256, 0, stream>>>(gmax, gsum, npg, dw, db, d_out, flag);
}

// Round 7
// 1080.114 us; speedup vs baseline: 1.0861x; 1.0861x over previous
//
#include <hip/hip_runtime.h>
#include <hip/hip_bf16.h>

typedef __hip_bfloat16 bf16;
typedef unsigned short u16;

#define N_NODES 100000
#define N_EDGES 1600000
#define F_IN 64
#define N_REL 8
#define N_GRAPH 256
#define N_HEAD 4
#define HC 128          // H*C
#define NBLK_SCAN 391   // ceil(100000/256)

__device__ __forceinline__ float lrelu(float x, float s) { return x >= 0.f ? x : s * x; }
__device__ __forceinline__ unsigned fenc(float f) {
  unsigned b = __float_as_uint(f);
  return (b & 0x80000000u) ? ~b : (b | 0x80000000u);
}
__device__ __forceinline__ float fdec(unsigned u) {
  float v = __uint_as_float((u & 0x80000000u) ? (u & 0x7fffffffu) : ~u);
  return fmaxf(fminf(v, 3e38f), -3e38f);
}
__device__ __forceinline__ float bf2f(bf16 v) { return __bfloat162float(v); }
__device__ __forceinline__ bf16 f2bf(float v) { return __float2bfloat16(v); }
__device__ __forceinline__ float lo_bf(unsigned u) { return __uint_as_float(u << 16); }
__device__ __forceinline__ float hi_bf(unsigned u) { return __uint_as_float(u & 0xFFFF0000u); }
__device__ __forceinline__ unsigned f2bfu(float v) {
  unsigned u = __float_as_uint(v);
  return (u + 0x7FFFu + ((u >> 16) & 1u)) >> 16;
}

// dtype-adaptive loads: BF=true -> bf16 array; BF=false -> fp32 array
template<bool BF> __device__ __forceinline__ float ldf(const void* p, size_t i) {
  if (BF) { u16 v = ((const u16*)p)[i]; return __uint_as_float(((unsigned)v) << 16); }
  else    { return ((const float*)p)[i]; }
}
// PAIR-index semantics: returns elements {2i, 2i+1}
template<bool BF> __device__ __forceinline__ float2 ldf2(const void* p, size_t i) {
  if (BF) { unsigned v = ((const unsigned*)p)[i]; return make_float2(lo_bf(v), hi_bf(v)); }
  else    { return ((const float2*)p)[i]; }
}

// ---- dtype probe ----
__global__ void k_probe(const u16* __restrict__ xr, int* __restrict__ flag) {
  int t = threadIdx.x;
  int c = 0;
  for (int i = t; i < 1024; i += 256) {
    unsigned e = (xr[i] >> 7) & 0xFFu;
    if (e >= 100u && e <= 140u) c++;
  }
  __shared__ int sc[256];
  sc[t] = c;
  __syncthreads();
  for (int s = 128; s; s >>= 1) { if (t < s) sc[t] += sc[t + s]; __syncthreads(); }
  if (t == 0) *flag = (sc[0] >= 800) ? 1 : 0;
}

// ---- GAT node transform: 16 nodes / 256 threads, weight columns in registers ----
// kh loop NOT unrolled (pragma unroll 1) so only one wreg[32] set is live.
template<bool BF>
__device__ __forceinline__ void gat_body(const void* x, const void* w, const void* att_s,
                                         const void* att_d, u16* __restrict__ h,
                                         float* __restrict__ a_src, float* __restrict__ a_dst,
                                         int n0, float* xs) {
  int tid = threadIdx.x;
  for (int i = tid; i < 16 * F_IN; i += 256)
    xs[i] = ldf<BF>(x, (size_t)(n0 + (i >> 6)) * F_IN + (i & 63));
  __syncthreads();
  int g = tid >> 7, c = tid & 127;
  float as_c = ldf<BF>(att_s, c), ad_c = ldf<BF>(att_d, c);
  float acc[8] = {0.f, 0.f, 0.f, 0.f, 0.f, 0.f, 0.f, 0.f};
#pragma unroll 1
  for (int kh = 0; kh < F_IN; kh += 32) {
    float wreg[32];
#pragma unroll
    for (int j = 0; j < 32; ++j) wreg[j] = ldf<BF>(w, (size_t)(kh + j) * HC + c);
#pragma unroll
    for (int n = 0; n < 8; ++n) {
      const float* xr = &xs[(g * 8 + n) * F_IN + kh];
#pragma unroll
      for (int j = 0; j < 32; j += 4) {
        float4 xv = *(const float4*)&xr[j];
        acc[n] += xv.x * wreg[j];
        acc[n] += xv.y * wreg[j + 1];
        acc[n] += xv.z * wreg[j + 2];
        acc[n] += xv.w * wreg[j + 3];
      }
    }
  }
  int l = tid & 63, head = c >> 5;
#pragma unroll
  for (int n = 0; n < 8; ++n) {
    int node = n0 + g * 8 + n;
    h[(size_t)node * HC + c] = (u16)f2bfu(acc[n]);
    float ps = acc[n] * as_c, pd = acc[n] * ad_c;
#pragma unroll
    for (int off = 16; off > 0; off >>= 1) {
      ps += __shfl_xor(ps, off, 64);
      pd += __shfl_xor(pd, off, 64);
    }
    if ((l & 31) == 0) {
      a_src[node * N_HEAD + head] = ps;
      a_dst[node * N_HEAD + head] = pd;
    }
  }
}

// ---- RGCN1 transform: 16 nodes x ALL 8 relations / 256 threads ----
template<bool BF>
__device__ __forceinline__ void xw1_body(const void* x, const void* rw1, bf16* __restrict__ xw1,
                                         int n0, float* xs) {
  int tid = threadIdx.x;
  for (int i = tid; i < 16 * F_IN; i += 256)
    xs[i] = ldf<BF>(x, (size_t)(n0 + (i >> 6)) * F_IN + (i & 63));
  __syncthreads();
  int r = tid >> 5, c = tid & 31;
  float acc[16] = {0.f, 0.f, 0.f, 0.f, 0.f, 0.f, 0.f, 0.f,
                   0.f, 0.f, 0.f, 0.f, 0.f, 0.f, 0.f, 0.f};
#pragma unroll 1
  for (int kh = 0; kh < F_IN; kh += 32) {
    float wreg[32];
#pragma unroll
    for (int j = 0; j < 32; ++j)
      wreg[j] = ldf<BF>(rw1, (size_t)(r * F_IN + kh + j) * 32 + c);
#pragma unroll
    for (int n = 0; n < 16; ++n) {
      const float* xr = &xs[n * F_IN + kh];
#pragma unroll
      for (int j = 0; j < 32; j += 4) {
        float4 xv = *(const float4*)&xr[j];
        acc[n] += xv.x * wreg[j];
        acc[n] += xv.y * wreg[j + 1];
        acc[n] += xv.z * wreg[j + 2];
        acc[n] += xv.w * wreg[j + 3];
      }
    }
  }
#pragma unroll
  for (int n = 0; n < 16; ++n)
    xw1[((size_t)r * N_NODES + (n0 + n)) * 32 + c] = f2bf(acc[n]);
}

// ---- merged: hist (blocks 0..6249) + gat (6250..12499) + xw1 (12500..18749) ----
// __launch_bounds__(256,4): lift the default 64-VGPR cap (was spilling wreg/acc
// to scratch: 2.7GB writes) to 128 while keeping 4 waves/EU.
__global__ void __launch_bounds__(256, 4)
k_gxh(const void* x, const void* w, const void* att_s, const void* att_d,
      u16* h, float* a_src, float* a_dst, const void* rw1, bf16* xw1,
      const int* __restrict__ ei, const int* __restrict__ etype,
      int* __restrict__ deg, int* __restrict__ cnt, const int* flag) {
  __shared__ __align__(16) float xs[16 * F_IN];
  int bid = blockIdx.x;
  if (bid < 6250) {
    int e = bid * 256 + threadIdx.x;   // 6250*256 == N_EDGES exactly
    int d = ei[N_EDGES + e], t = etype[e];
    atomicAdd(&deg[d], 1);
    atomicAdd(&cnt[d * N_REL + t], 1);
  } else if (bid < 12500) {
    int n0 = (bid - 6250) * 16;
    if (__builtin_amdgcn_readfirstlane(*flag))
      gat_body<true>(x, w, att_s, att_d, h, a_src, a_dst, n0, xs);
    else
      gat_body<false>(x, w, att_s, att_d, h, a_src, a_dst, n0, xs);
  } else {
    int n0 = (bid - 12500) * 16;
    if (__builtin_amdgcn_readfirstlane(*flag)) xw1_body<true>(x, rw1, xw1, n0, xs);
    else xw1_body<false>(x, rw1, xw1, n0, xs);
  }
}

// ---- 2-level exclusive scan ----
__global__ void k_scan_a(const int* __restrict__ deg, int* __restrict__ rowptr,
                         int* __restrict__ scanblk) {
  __shared__ int buf[256];
  int tid = threadIdx.x;
  int i = blockIdx.x * 256 + tid;
  int v = (i < N_NODES) ? deg[i] : 0;
  buf[tid] = v;
  __syncthreads();
  for (int st = 1; st < 256; st <<= 1) {
    int t = buf[tid];
    int a = (tid >= st) ? buf[tid - st] : 0;
    __syncthreads();
    buf[tid] = t + a;
    __syncthreads();
  }
  if (i < N_NODES) rowptr[i] = buf[tid] - v;
  if (tid == 255) scanblk[blockIdx.x] = buf[255];
}
__global__ void k_scan_b(int* __restrict__ scanblk) {
  __shared__ int buf[512];
  int tid = threadIdx.x;
  int v = (tid < NBLK_SCAN) ? scanblk[tid] : 0;
  buf[tid] = v;
  __syncthreads();
  for (int st = 1; st < 512; st <<= 1) {
    int t = buf[tid];
    int a = (tid >= st) ? buf[tid - st] : 0;
    __syncthreads();
    buf[tid] = t + a;
    __syncthreads();
  }
  if (tid < NBLK_SCAN) scanblk[tid] = buf[tid] - v;
}
__global__ void k_scan_c(int* __restrict__ rowptr, int* __restrict__ wp,
                         const int* __restrict__ scanblk) {
  int i = blockIdx.x * 256 + threadIdx.x;
  if (i < N_NODES) {
    int val = rowptr[i] + scanblk[blockIdx.x];
    rowptr[i] = val;
    wp[i] = val;
  } else if (i == N_NODES) {
    rowptr[N_NODES] = N_EDGES;
  }
}

// ---- scatter edges into CSR order; store logits per pos ----
__global__ void k_scatter(const int* __restrict__ ei, const int* __restrict__ etype,
                          const float* __restrict__ a_src, const float* __restrict__ a_dst,
                          int* __restrict__ wp, unsigned* __restrict__ csr,
                          float4* __restrict__ p_logit) {
  int e = blockIdx.x * 256 + threadIdx.x;
  if (e >= N_EDGES) return;
  int sn = ei[e], d = ei[N_EDGES + e], t = etype[e];
  int pos = atomicAdd(&wp[d], 1);
  csr[pos] = (unsigned)sn | ((unsigned)t << 20);
  const float4 as = *(const float4*)&a_src[sn * 4];
  const float4 ad = *(const float4*)&a_dst[d * 4];
  float4 lg;
  lg.x = lrelu(as.x + ad.x, 0.2f);
  lg.y = lrelu(as.y + ad.y, 0.2f);
  lg.z = lrelu(as.z + ad.z, 0.2f);
  lg.w = lrelu(as.w + ad.w, 0.2f);
  p_logit[pos] = lg;
}

// ---- GAT aggregate with INLINE segment softmax (round-2 proven shape) ----
template<bool BF>
__device__ __forceinline__ void agg_body(const int* __restrict__ rowptr,
                                         const unsigned* __restrict__ csr,
                                         const float* __restrict__ plog,
                                         const uint2* __restrict__ hu2, const void* gbias,
                                         const void* d1w, const void* d1b,
                                         const int* __restrict__ batch,
                                         unsigned* __restrict__ gmax, int* __restrict__ npg,
                                         float (*os)[132], int bid) {
  int tid = threadIdx.x;
  int wave = tid >> 6, l = tid & 63;
  int d = bid * 4 + wave;
  int base = rowptr[d];
  int deg = rowptr[d + 1] - base;
  // --- softmax stats in-register ---
  float m = -1e30f, si;
  {
    int hd = l & 3, sl = l >> 2;
    for (int i = sl; i < deg; i += 16) m = fmaxf(m, plog[(size_t)(base + i) * 4 + hd]);
    m = fmaxf(m, __shfl_xor(m, 4, 64));
    m = fmaxf(m, __shfl_xor(m, 8, 64));
    m = fmaxf(m, __shfl_xor(m, 16, 64));
    m = fmaxf(m, __shfl_xor(m, 32, 64));
    float s = 0.f;
    for (int i = sl; i < deg; i += 16) s += __expf(plog[(size_t)(base + i) * 4 + hd] - m);
    s += __shfl_xor(s, 4, 64);
    s += __shfl_xor(s, 8, 64);
    s += __shfl_xor(s, 16, 64);
    s += __shfl_xor(s, 32, 64);
    si = (deg > 0) ? 1.f / s : 0.f;
  }
  int slot = l >> 5, cl = l & 31;   // lane covers channels 4cl..4cl+3 of edge-slot `slot`
  int head = cl >> 3;
  float mh = __shfl(m, head, 64);   // lane 0..3 holds fully-reduced (m,si) for head 0..3
  float sih = __shfl(si, head, 64);
  float a0 = 0.f, a1 = 0.f, a2 = 0.f, a3 = 0.f;
  int i = slot;
  for (; i + 6 < deg; i += 8) {
    unsigned sp0 = csr[base + i],     sp1 = csr[base + i + 2];
    unsigned sp2 = csr[base + i + 4], sp3 = csr[base + i + 6];
    float av0 = __expf(plog[(size_t)(base + i) * 4 + head] - mh) * sih;
    float av1 = __expf(plog[(size_t)(base + i + 2) * 4 + head] - mh) * sih;
    float av2 = __expf(plog[(size_t)(base + i + 4) * 4 + head] - mh) * sih;
    float av3 = __expf(plog[(size_t)(base + i + 6) * 4 + head] - mh) * sih;
    uint2 h0 = hu2[(size_t)(sp0 & 0xFFFFF) * 32 + cl];
    uint2 h1 = hu2[(size_t)(sp1 & 0xFFFFF) * 32 + cl];
    uint2 h2 = hu2[(size_t)(sp2 & 0xFFFFF) * 32 + cl];
    uint2 h3 = hu2[(size_t)(sp3 & 0xFFFFF) * 32 + cl];
    a0 += lo_bf(h0.x) * av0 + lo_bf(h1.x) * av1 + lo_bf(h2.x) * av2 + lo_bf(h3.x) * av3;
    a1 += hi_bf(h0.x) * av0 + hi_bf(h1.x) * av1 + hi_bf(h2.x) * av2 + hi_bf(h3.x) * av3;
    a2 += lo_bf(h0.y) * av0 + lo_bf(h1.y) * av1 + lo_bf(h2.y) * av2 + lo_bf(h3.y) * av3;
    a3 += hi_bf(h0.y) * av0 + hi_bf(h1.y) * av1 + hi_bf(h2.y) * av2 + hi_bf(h3.y) * av3;
  }
  for (; i < deg; i += 2) {
    unsigned sp = csr[base + i];
    float av = __expf(plog[(size_t)(base + i) * 4 + head] - mh) * sih;
    uint2 hv = hu2[(size_t)(sp & 0xFFFFF) * 32 + cl];
    a0 += lo_bf(hv.x) * av;
    a1 += hi_bf(hv.x) * av;
    a2 += lo_bf(hv.y) * av;
    a3 += hi_bf(hv.y) * av;
  }
  a0 += __shfl_xor(a0, 32, 64);
  a1 += __shfl_xor(a1, 32, 64);
  a2 += __shfl_xor(a2, 32, 64);
  a3 += __shfl_xor(a3, 32, 64);
  if (slot == 0) {
    os[wave][4 * cl + 0] = lrelu(a0 + ldf<BF>(gbias, 4 * cl + 0), 0.01f);
    os[wave][4 * cl + 1] = lrelu(a1 + ldf<BF>(gbias, 4 * cl + 1), 0.01f);
    os[wave][4 * cl + 2] = lrelu(a2 + ldf<BF>(gbias, 4 * cl + 2), 0.01f);
    os[wave][4 * cl + 3] = lrelu(a3 + ldf<BF>(gbias, 4 * cl + 3), 0.01f);
  }
  __syncthreads();
  if (tid < 64) {
    int node = tid >> 4, out = tid & 15;
    float acc = ldf<BF>(d1b, out);
#pragma unroll
    for (int k = 0; k < HC; ++k) acc += os[node][k] * ldf<BF>(d1w, (size_t)k * 16 + out);
    acc = lrelu(acc, 0.01f);
    atomicMax(&gmax[batch[bid * 4 + node] * 16 + out], fenc(acc));
  }
  if (tid < 4) atomicAdd(&npg[batch[bid * 4 + tid]], 1);
}

// ---- RGCN1 gather (round-2 proven shape) ----
template<bool BF>
__device__ __forceinline__ void ragg1_body(const int* __restrict__ rowptr,
                                           const unsigned* __restrict__ csr,
                                           const int* __restrict__ cnt,
                                           const unsigned* __restrict__ xw, const void* x,
                                           const void* root1, const void* rb1,
                                           float* __restrict__ z1, float* sh, int bid) {
  float (*xs)[F_IN] = (float(*)[F_IN])sh;
  float (*cinv)[N_REL] = (float(*)[N_REL])(sh + 4 * F_IN);
  int tid = threadIdx.x;
  int n0 = bid * 4;  // 25000 blocks, exact
  {
    int nn = n0 + (tid >> 6);
    xs[tid >> 6][tid & 63] = ldf<BF>(x, (size_t)nn * F_IN + (tid & 63));
  }
  if (tid < 32) {
    int cv = cnt[(n0 + (tid >> 3)) * N_REL + (tid & 7)];
    cinv[tid >> 3][tid & 7] = (cv > 0) ? 1.f / (float)cv : 0.f;
  }
  __syncthreads();
  int wave = tid >> 6, l = tid & 63;
  int slot = l >> 4, cl = l & 15;   // channels 2cl, 2cl+1
  int n = n0 + wave;
  int base = rowptr[n], deg = rowptr[n + 1] - base;
  float a0 = 0.f, a1 = 0.f;
  int i = slot;
  for (; i + 4 < deg; i += 8) {
    unsigned sp0 = csr[base + i], sp1 = csr[base + i + 4];
    int t0 = sp0 >> 20, t1 = sp1 >> 20;
    unsigned v0 = xw[((size_t)t0 * N_NODES + (sp0 & 0xFFFFF)) * 16 + cl];
    unsigned v1 = xw[((size_t)t1 * N_NODES + (sp1 & 0xFFFFF)) * 16 + cl];
    float c0 = cinv[wave][t0], c1 = cinv[wave][t1];
    a0 += lo_bf(v0) * c0 + lo_bf(v1) * c1;
    a1 += hi_bf(v0) * c0 + hi_bf(v1) * c1;
  }
  if (i < deg) {
    unsigned sp = csr[base + i];
    int t = sp >> 20;
    unsigned v = xw[((size_t)t * N_NODES + (sp & 0xFFFFF)) * 16 + cl];
    float c0 = cinv[wave][t];
    a0 += lo_bf(v) * c0;
    a1 += hi_bf(v) * c0;
  }
  // root part: slot covers k in [slot*16, slot*16+16)
#pragma unroll
  for (int kk = 0; kk < 16; ++kk) {
    int k = slot * 16 + kk;
    float xv = xs[wave][k];
    float2 wv = ldf2<BF>(root1, (size_t)k * 16 + cl);   // pair idx: elements k*32+2cl,+1
    a0 += xv * wv.x;
    a1 += xv * wv.y;
  }
  a0 += __shfl_xor(a0, 16, 64); a0 += __shfl_xor(a0, 32, 64);
  a1 += __shfl_xor(a1, 16, 64); a1 += __shfl_xor(a1, 32, 64);
  if (slot == 0) {
    z1[(size_t)n * 32 + 2 * cl]     = fmaxf(a0 + ldf<BF>(rb1, 2 * cl), 0.f);
    z1[(size_t)n * 32 + 2 * cl + 1] = fmaxf(a1 + ldf<BF>(rb1, 2 * cl + 1), 0.f);
  }
}

// ---- merged: GAT aggregate (blocks 0..24999) + RGCN1 gather (25000..49999) ----
__global__ void k_aggragg1(const int* rowptr, const unsigned* csr, const float* plog,
                           const u16* h, const void* gbias, const void* d1w, const void* d1b,
                           const int* batch, unsigned* gmax, int* npg,
                           const int* cnt, const bf16* xw1, const void* x,
                           const void* root1, const void* rb1, float* z1, const int* flag) {
  __shared__ __align__(16) float sh[544];   // union: os[4][132]=528 | xs[4][64]+cinv[4][8]=288
  int bf = __builtin_amdgcn_readfirstlane(*flag);
  if (blockIdx.x < 25000) {
    if (bf) agg_body<true>(rowptr, csr, plog, (const uint2*)h, gbias, d1w, d1b,
                           batch, gmax, npg, (float(*)[132])sh, blockIdx.x);
    else    agg_body<false>(rowptr, csr, plog, (const uint2*)h, gbias, d1w, d1b,
                            batch, gmax, npg, (float(*)[132])sh, blockIdx.x);
  } else {
    if (bf) ragg1_body<true>(rowptr, csr, cnt, (const unsigned*)xw1, x, root1, rb1, z1,
                             sh, blockIdx.x - 25000);
    else    ragg1_body<false>(rowptr, csr, cnt, (const unsigned*)xw1, x, root1, rb1, z1,
                              sh, blockIdx.x - 25000);
  }
}

// ---- RGCN2: zw2[r,n,16] = z1[n] @ rw2[r] ----
template<bool BF>
__device__ __forceinline__ void zw2_body(const float* __restrict__ z1, const void* rw2,
                                         bf16* __restrict__ zw2) {
  __shared__ float zs[16][32];
  int tid = threadIdx.x;
  int n0 = blockIdx.x * 16;
  for (int i = tid; i < 16 * 32; i += 256) {
    int nn = n0 + (i >> 5);
    zs[i >> 5][i & 31] = (nn < N_NODES) ? z1[(size_t)nn * 32 + (i & 31)] : 0.f;
  }
  __syncthreads();
  int nl = tid >> 4, c = tid & 15;
  int n = n0 + nl, r = blockIdx.y;
  float acc = 0.f;
#pragma unroll
  for (int k = 0; k < 32; ++k) acc += zs[nl][k] * ldf<BF>(rw2, (size_t)(r * 32 + k) * 16 + c);
  if (n < N_NODES) zw2[((size_t)r * N_NODES + n) * 16 + c] = f2bf(acc);
}
__global__ void k_zw2(const float* z1, const void* rw2, bf16* zw2, const int* flag) {
  if (__builtin_amdgcn_readfirstlane(*flag)) zw2_body<true>(z1, rw2, zw2);
  else zw2_body<false>(z1, rw2, zw2);
}

// ---- RGCN2 gather (round-2 proven shape): 4 nodes/block, 8 slots x 8 lanes x u32 ----
template<bool BF>
__device__ __forceinline__ void ragg2_body(const int* __restrict__ rowptr,
                                           const unsigned* __restrict__ csr,
                                           const int* __restrict__ cnt,
                                           const unsigned* __restrict__ zw,
                                           const float* __restrict__ z1, const void* root2,
                                           const void* rb2, const int* __restrict__ batch,
                                           float* __restrict__ gsum) {
  __shared__ float zs[4][33];
  __shared__ float cinv[4][N_REL];
  int tid = threadIdx.x;
  int n0 = blockIdx.x * 4;  // grid 25000, exact
  if (tid < 128) {
    int nn = n0 + (tid >> 5);
    zs[tid >> 5][tid & 31] = z1[(size_t)nn * 32 + (tid & 31)];
  }
  if (tid < 32) {
    int cv = cnt[(n0 + (tid >> 3)) * N_REL + (tid & 7)];
    cinv[tid >> 3][tid & 7] = (cv > 0) ? 1.f / (float)cv : 0.f;
  }
  __syncthreads();
  int wave = tid >> 6, l = tid & 63;
  int slot = l >> 3, cl = l & 7;   // channels 2cl, 2cl+1 of 16
  int n = n0 + wave;
  int base = rowptr[n], deg = rowptr[n + 1] - base;
  float a0 = 0.f, a1 = 0.f;
  int i = slot;
  for (; i + 8 < deg; i += 16) {
    unsigned sp0 = csr[base + i], sp1 = csr[base + i + 8];
    int t0 = sp0 >> 20, t1 = sp1 >> 20;
    unsigned v0 = zw[((size_t)t0 * N_NODES + (sp0 & 0xFFFFF)) * 8 + cl];
    unsigned v1 = zw[((size_t)t1 * N_NODES + (sp1 & 0xFFFFF)) * 8 + cl];
    float c0 = cinv[wave][t0], c1 = cinv[wave][t1];
    a0 += lo_bf(v0) * c0 + lo_bf(v1) * c1;
    a1 += hi_bf(v0) * c0 + hi_bf(v1) * c1;
  }
  if (i < deg) {
    unsigned sp = csr[base + i];
    int t = sp >> 20;
    unsigned v = zw[((size_t)t * N_NODES + (sp & 0xFFFFF)) * 8 + cl];
    float c0 = cinv[wave][t];
    a0 += lo_bf(v) * c0;
    a1 += hi_bf(v) * c0;
  }
  // root part: slot covers k in [slot*4, slot*4+4)
#pragma unroll
  for (int kk = 0; kk < 4; ++kk) {
    int k = slot * 4 + kk;
    float zv = zs[wave][k];
    float2 wv = ldf2<BF>(root2, (size_t)k * 8 + cl);   // pair idx: elements k*16+2cl,+1
    a0 += zv * wv.x;
    a1 += zv * wv.y;
  }
  a0 += __shfl_xor(a0, 8, 64); a0 += __shfl_xor(a0, 16, 64); a0 += __shfl_xor(a0, 32, 64);
  a1 += __shfl_xor(a1, 8, 64); a1 += __shfl_xor(a1, 16, 64); a1 += __shfl_xor(a1, 32, 64);
  if (slot == 0) {
    float z2a = fmaxf(a0 + ldf<BF>(rb2, 2 * cl), 0.f);
    float z2b = fmaxf(a1 + ldf<BF>(rb2, 2 * cl + 1), 0.f);
    int g = batch[n];
    atomicAdd(&gsum[g * 16 + 2 * cl], z2a);
    atomicAdd(&gsum[g * 16 + 2 * cl + 1], z2b);
  }
}
__global__ void k_ragg2(const int* rowptr, const unsigned* csr, const int* cnt,
                        const bf16* zw2, const float* z1, const void* root2, const void* rb2,
                        const int* batch, float* gsum, const int* flag) {
  if (__builtin_amdgcn_readfirstlane(*flag))
    ragg2_body<true>(rowptr, csr, cnt, (const unsigned*)zw2, z1, root2, rb2, batch, gsum);
  else
    ragg2_body<false>(rowptr, csr, cnt, (const unsigned*)zw2, z1, root2, rb2, batch, gsum);
}

// ---- final ----
template<bool BF>
__device__ __forceinline__ void final_body(const unsigned* __restrict__ gmax,
                                           const float* __restrict__ gsum,
                                           const int* __restrict__ npg, const void* dw,
                                           const void* db, void* out) {
  int g = threadIdx.x;
  if (g >= N_GRAPH) return;
  float acc = ldf<BF>(db, 0);
  int np = npg[g]; if (np < 1) np = 1;
  float inv = 1.f / (float)np;
#pragma unroll
  for (int c = 0; c < 16; ++c) {
    acc += fdec(gmax[g * 16 + c]) * ldf<BF>(dw, c);
    acc += (gsum[g * 16 + c] * inv) * ldf<BF>(dw, 16 + c);
  }
  if (BF) ((bf16*)out)[g] = f2bf(acc);
  else ((float*)out)[g] = acc;
}
__global__ void k_final(const unsigned* gmax, const float* gsum, const int* npg,
                        const void* dw, const void* db, void* out, const int* flag) {
  if (__builtin_amdgcn_readfirstlane(*flag)) final_body<true>(gmax, gsum, npg, dw, db, out);
  else final_body<false>(gmax, gsum, npg, dw, db, out);
}

extern "C" void kernel_launch(void* const* d_in, const int* in_sizes, int n_in,
                              void* d_out, int out_size, void* d_ws, size_t ws_size,
                              hipStream_t stream) {
  const void* x        = d_in[0];
  const int*  ei       = (const int*)d_in[1];
  const int*  etype    = (const int*)d_in[2];
  const int*  batch    = (const int*)d_in[3];
  const void* gat_w    = d_in[4];
  const void* att_src  = d_in[5];
  const void* att_dst  = d_in[6];
  const void* gat_bias = d_in[7];
  const void* d1w      = d_in[8];
  const void* d1b      = d_in[9];
  const void* rw1      = d_in[10];
  const void* root1    = d_in[11];
  const void* rb1      = d_in[12];
  const void* rw2      = d_in[13];
  const void* root2    = d_in[14];
  const void* rb2      = d_in[15];
  const void* dw       = d_in[16];
  const void* db       = d_in[17];

  // ---- workspace layout (~129.2 MB) ----
  char* ws = (char*)d_ws;
  const size_t o_h     = 0;           // u16  N*128 (25.6MB)  — GAT table; zw2 overlays later
  const size_t o_plog  = 25600000;    // f32  E*4   (25.6MB)  — logits (read by agg in place)
  const size_t o_xw1   = 51200000;    // bf16 R*N*32 (51.2MB) — RGCN1 per-relation transform
  const size_t o_zw2   = 0;           // bf16 R*N*16 (25.6MB) — RGCN2, overlays h (dead)
  const size_t o_asrc  = 102400000;   // f32 N*4 (1.6MB) — attention src coeffs
  const size_t o_adst  = 104000000;   // f32 N*4 (1.6MB) — attention dst coeffs
  const size_t o_deg   = 105600000;   // i32 N (0.4MB)
  const size_t o_rowp  = 106000000;   // i32 N+1
  const size_t o_wp    = 106400016;   // i32 N
  const size_t o_cnt   = 106800016;   // i32 N*8 (3.2MB)
  const size_t o_csr   = 110000016;   // u32 E (6.4MB)
  const size_t o_z1    = 116400016;   // f32 N*32 (12.8MB)
  const size_t o_sblk  = 129200016;   // i32 NBLK_SCAN
  const size_t o_gmax  = 129201600;   // u32 G*16
  const size_t o_gsum  = 129217984;   // f32 G*16
  const size_t o_npg   = 129234368;   // i32 G
  const size_t o_flag  = 129235392;   // i32
  const size_t total   = 129235396;
  if (ws_size < total) return;

  u16*      h      = (u16*)(ws + o_h);
  float*    plog   = (float*)(ws + o_plog);
  bf16*     xw1    = (bf16*)(ws + o_xw1);
  bf16*     zw2    = (bf16*)(ws + o_zw2);
  float*    a_src  = (float*)(ws + o_asrc);
  float*    a_dst  = (float*)(ws + o_adst);
  int*      deg    = (int*)(ws + o_deg);
  int*      rowptr = (int*)(ws + o_rowp);
  int*      wp     = (int*)(ws + o_wp);
  int*      cnt    = (int*)(ws + o_cnt);
  unsigned* csr    = (unsigned*)(ws + o_csr);
  float*    z1     = (float*)(ws + o_z1);
  int*      sblk   = (int*)(ws + o_sblk);
  unsigned* gmax   = (unsigned*)(ws + o_gmax);
  float*    gsum   = (float*)(ws + o_gsum);
  int*      npg    = (int*)(ws + o_npg);
  int*      flag   = (int*)(ws + o_flag);

  // dtype probe
  k_probe<<<1, 256, 0, stream>>>((const u16*)x, flag);

  // zero-init: deg..cnt contiguous, and gmax/gsum/npg
  hipMemsetAsync(ws + o_deg, 0, o_csr - o_deg, stream);
  hipMemsetAsync(ws + o_gmax, 0, 33792, stream);

  // merged: edge histogram + GAT node transform + RGCN1 per-relation transform
  k_gxh<<<18750, 256, 0, stream>>>(x, gat_w, att_src, att_dst, h, a_src, a_dst,
                                   rw1, xw1, ei, etype, deg, cnt, flag);

  // CSR scan + scatter (logits stored per CSR pos)
  k_scan_a<<<NBLK_SCAN, 256, 0, stream>>>(deg, rowptr, sblk);
  k_scan_b<<<1, 512, 0, stream>>>(sblk);
  k_scan_c<<<NBLK_SCAN, 256, 0, stream>>>(rowptr, wp, sblk);
  k_scatter<<<(N_EDGES + 255) / 256, 256, 0, stream>>>(ei, etype, a_src, a_dst, wp, csr,
                                                       (float4*)plog);

  // merged: GAT aggregate (inline softmax) + RGCN1 gather — two latency-bound
  // gather populations share the CUs for more loads in flight
  k_aggragg1<<<50000, 256, 0, stream>>>(rowptr, csr, plog, h, gat_bias, d1w, d1b,
                                        batch, gmax, npg, cnt, xw1, x, root1, rb1, z1, flag);

  // RGCN2 (zw2 overlays h — GAT phase done)
  k_zw2<<<dim3((N_NODES + 15) / 16, N_REL), 256, 0, stream>>>(z1, rw2, zw2, flag);
  k_ragg2<<<N_NODES / 4, 256, 0, stream>>>(rowptr, csr, cnt, zw2, z1, root2, rb2,
                                           batch, gsum, flag);

  // fuse
  k_final<<<1, 256, 0, stream>>>(gmax, gsum, npg, dw, db, d_out, flag);
}